// Round 7
// baseline (383.110 us; speedup 1.0000x reference)
//
#include <hip/hip_runtime.h>
#include <hip/hip_bf16.h>
#include <math.h>

typedef __bf16 bf16;
typedef __bf16 bf16x8 __attribute__((ext_vector_type(8)));
typedef __bf16 bf16x4 __attribute__((ext_vector_type(4)));
typedef float floatx4 __attribute__((ext_vector_type(4)));

typedef const __attribute__((address_space(1))) void* gas_t;
typedef __attribute__((address_space(3))) void* las_t;

#define NPIX 4096
#define DCH 256

// ---------------- workspace layout (bytes) ----------------
#define OFF_XB   ((size_t)0)            // bf16 [8192][256]      4 MB
#define OFF_WB   ((size_t)4194304)      // bf16 [768][256]       384 KB
#define OFF_Q    ((size_t)4587520)      // bf16 [8192][256]      4 MB
#define OFF_K    ((size_t)8781824)      // bf16 [8192][256]      4 MB
#define OFF_V    ((size_t)12976128)     // bf16 [8192][256]      4 MB
#define OFF_E    ((size_t)17170432)     // bf16 [2][4096][4096]  64 MB
#define OFF_VPP  ((size_t)84279296)     // bf16 [2][256][4096]   4 MB
#define OFF_RP   ((size_t)88473600)     // f32  [2][16][4096]    512 KB (rowsum partials per 256-m-tile)
#define OFF_CP   ((size_t)89522176)     // f32  [2][16][4096]    512 KB (colsum partials per 256-row n-group)
#define OFF_CTR  ((size_t)90046464)     // int  [96]             (32 pass_a group ctrs + 64 pass_c group ctrs)
#define OFF_PART ((size_t)91619328)     // bf16 [2][4][256][4096] 16 MB (split-K partials)

// global->LDS DMA staging, 16B/lane, XOR swizzle applied on the GLOBAL side
// (LDS dest must stay wave-uniform-base + lane*16). LDS[row][seg] = global[row][seg^(row&7)].
__device__ __forceinline__ void stage_tile(const bf16* __restrict__ g0, size_t rstride,
                                           bf16* lds, int t) {
  const int wbase = (t >> 6) << 6;
#pragma unroll
  for (int i = 0; i < 4; i++) {
    int slot = i * 256 + t;
    int row = slot >> 3, seg = slot & 7;
    const bf16* g = g0 + (size_t)row * rstride + ((seg ^ (row & 7)) << 3);
    bf16* l = lds + (size_t)(i * 256 + wbase) * 8;
    __builtin_amdgcn_global_load_lds((gas_t)g, (las_t)l, 16, 0, 0);
  }
}

// 512-thread variant: 256 rows x 64 cols per call (4 loads/thread).
__device__ __forceinline__ void stage_tile512(const bf16* __restrict__ g0, size_t rstride,
                                              bf16* lds, int t) {
  const int wbase = (t >> 6) << 6;
#pragma unroll
  for (int i = 0; i < 4; i++) {
    int slot = i * 512 + t;
    int row = slot >> 3, seg = slot & 7;
    const bf16* g = g0 + (size_t)row * rstride + ((seg ^ (row & 7)) << 3);
    bf16* l = lds + (size_t)(i * 512 + wbase) * 8;
    __builtin_amdgcn_global_load_lds((gas_t)g, (las_t)l, 16, 0, 0);
  }
}

// 512-thread variant: 128 rows x 64 cols per call (2 loads/thread).
__device__ __forceinline__ void stage_tile128_512(const bf16* __restrict__ g0, size_t rstride,
                                                  bf16* lds, int t) {
  const int wbase = (t >> 6) << 6;
#pragma unroll
  for (int i = 0; i < 2; i++) {
    int slot = i * 512 + t;
    int row = slot >> 3, seg = slot & 7;
    const bf16* g = g0 + (size_t)row * rstride + ((seg ^ (row & 7)) << 3);
    bf16* l = lds + (size_t)(i * 512 + wbase) * 8;
    __builtin_amdgcn_global_load_lds((gas_t)g, (las_t)l, 16, 0, 0);
  }
}

// ============ K0: prep = transpose x to [n][c] bf16 (y<4) + convert W (y==4) + zero counters ============
__global__ __launch_bounds__(256) void prep(
    const float* __restrict__ x, const float* __restrict__ W,
    bf16* __restrict__ xb, bf16* __restrict__ wb, int* __restrict__ ctrs)
{
  const int t = threadIdx.x;
  if (blockIdx.y == 4) {
    if (blockIdx.x == 0 && blockIdx.z == 0 && t < 96) ctrs[t] = 0;
    int gid = (blockIdx.z * 64 + blockIdx.x) * 256 + t;
    for (int i = gid; i < 49152; i += 32768) {
      float4 v = *(const float4*)(W + (size_t)i * 4);
      bf16x4 pk = { (bf16)v.x, (bf16)v.y, (bf16)v.z, (bf16)v.w };
      *(bf16x4*)(wb + (size_t)i * 4) = pk;
    }
    return;
  }
  __shared__ float ts[64][65];
  const int b = blockIdx.z, n0 = blockIdx.x * 64, c0 = blockIdx.y * 64;
  const float* xp = x + ((size_t)b * DCH + c0) * NPIX + n0;
  for (int i = 0; i < 4; i++) {
    int slot = t + i * 256;
    int c = slot >> 4, nq = (slot & 15) * 4;
    float4 v = *(const float4*)(xp + (size_t)c * NPIX + nq);
    ts[c][nq + 0] = v.x; ts[c][nq + 1] = v.y; ts[c][nq + 2] = v.z; ts[c][nq + 3] = v.w;
  }
  __syncthreads();
  for (int i = 0; i < 2; i++) {
    int slot = t + i * 256;
    int n = slot >> 3, cq = (slot & 7) * 8;
    bf16x8 pk;
    for (int j = 0; j < 8; j++) pk[j] = (bf16)ts[cq + j][n];
    *(bf16x8*)(xb + ((size_t)b * NPIX + n0 + n) * DCH + c0 + cq) = pk;
  }
}

// ============ K1: 1x1 conv as bf16 MFMA GEMM (pipelined dbuf) ============
__global__ __launch_bounds__(256) void conv_mfma(
    const bf16* __restrict__ xb, const bf16* __restrict__ wb,
    const float* __restrict__ bias,
    bf16* __restrict__ qb, bf16* __restrict__ kb, bf16* __restrict__ vb)
{
  __shared__ bf16 at[2][128 * 64];
  __shared__ bf16 bt[2][128 * 64];
  __shared__ float bs[128];
  const int t  = threadIdx.x;
  const int n0 = blockIdx.x * 128;
  const int o0 = blockIdx.y * 128;
  if (t < 128) bs[t] = bias[o0 + t];
  const int lane = t & 63, wave = t >> 6;
  const int wm = wave >> 1, wn = wave & 1;
  const int l15 = lane & 15, quad = lane >> 4;
  const int l7 = l15 & 7;

  stage_tile(wb + (size_t)o0 * DCH, DCH, at[0], t);
  stage_tile(xb + (size_t)n0 * DCH, DCH, bt[0], t);

  floatx4 acc[4][4];
  for (int i=0;i<4;i++) for (int j=0;j<4;j++) for (int r=0;r<4;r++) acc[i][j][r] = 0.f;

#pragma unroll
  for (int kidx = 0; kidx < 4; kidx++) {
    const int cur = kidx & 1;
    if (kidx < 3) {
      stage_tile(wb + (size_t)o0 * DCH + (kidx + 1) * 64, DCH, at[cur ^ 1], t);
      stage_tile(xb + (size_t)n0 * DCH + (kidx + 1) * 64, DCH, bt[cur ^ 1], t);
      asm volatile("s_waitcnt vmcnt(8)" ::: "memory");
    } else {
      asm volatile("s_waitcnt vmcnt(0)" ::: "memory");
    }
    __builtin_amdgcn_s_barrier();
    asm volatile("" ::: "memory");
    for (int kk = 0; kk < 2; kk++) {
      bf16x8 af[4], bfr[4];
      int sw = ((kk * 4 + quad) ^ l7) * 8;
      for (int f = 0; f < 4; f++)
        af[f]  = *(const bf16x8*)&at[cur][(wm*64 + f*16 + l15)*64 + sw];
      for (int f = 0; f < 4; f++)
        bfr[f] = *(const bf16x8*)&bt[cur][(wn*64 + f*16 + l15)*64 + sw];
      for (int fm = 0; fm < 4; fm++)
        for (int fn = 0; fn < 4; fn++)
          acc[fm][fn] = __builtin_amdgcn_mfma_f32_16x16x32_bf16(af[fm], bfr[fn], acc[fm][fn], 0, 0, 0);
    }
    asm volatile("" ::: "memory");
    __builtin_amdgcn_s_barrier();
  }

  const float scale = (o0 < 512) ? 0.25f : 1.0f;
  bf16* dst; int od;
  if (o0 < 256)      { dst = qb; od = o0; }
  else if (o0 < 512) { dst = kb; od = o0 - 256; }
  else               { dst = vb; od = o0 - 512; }

  for (int fm = 0; fm < 4; fm++)
    for (int fn = 0; fn < 4; fn++) {
      int o_l = wm*64 + fm*16 + quad*4;
      int n_g = n0 + wn*64 + fn*16 + l15;
      bf16x4 pk;
      for (int r = 0; r < 4; r++)
        pk[r] = (bf16)((acc[fm][fn][r] + bs[o_l + r]) * scale);
      *(bf16x4*)(dst + (size_t)n_g * DCH + od + o_l) = pk;
    }
}

// ============ K2: pass A — 256x256 tile, 8 waves, dbuf counted-vmcnt. E = exp(q k^T) via
//   LDS-transpose epilogue; rowpart per 256-m-tile. FUSED col_pass: the 16th (last) block of
//   each 256-row E-stripe streams the stripe (L2/L3-warm) to produce the colsum partial. ============
__global__ __launch_bounds__(512, 2) void pass_a(
    const bf16* __restrict__ qb, const bf16* __restrict__ kb,
    bf16* __restrict__ E, float* __restrict__ rowpartG,
    float* __restrict__ cpart, int* __restrict__ ctrA, float logm)
{
  __shared__ bf16 smem[65536];   // 128 KB staging; epilogue: ep 256x256 bf16; closer: eus f32[256]
  __shared__ int lastflag;
  const int bx = blockIdx.x, by = blockIdx.y, b = blockIdx.z;  // bx fastest -> stripes close staggered
  qb += (size_t)b * NPIX * DCH;
  kb += (size_t)b * NPIX * DCH;
  E  += (size_t)b * NPIX * NPIX;
  float* rp = rowpartG + ((size_t)b * 16 + bx) * NPIX;
  const int t  = threadIdx.x;
  const int m0 = bx * 256;
  const int n0 = by * 256;
  const int lane = t & 63, wave = t >> 6;
  const int wm = wave >> 2, wn = wave & 3;       // 2 m-halves x 4 n-quarters
  const int l15 = lane & 15, quad = lane >> 4;
  const int l7 = l15 & 7;
  bf16* kt0 = smem;              // [2][16384]
  bf16* qt0 = smem + 32768;      // [2][16384]

  stage_tile512(kb + (size_t)m0 * DCH, DCH, kt0, t);
  stage_tile512(qb + (size_t)n0 * DCH, DCH, qt0, t);

  floatx4 acc[8][4];
  for (int i=0;i<8;i++) for (int j=0;j<4;j++) for (int r=0;r<4;r++) acc[i][j][r] = 0.f;

#pragma unroll
  for (int kidx = 0; kidx < 4; kidx++) {
    const int cur = kidx & 1;
    if (kidx < 3) {
      stage_tile512(kb + (size_t)m0 * DCH + (kidx + 1) * 64, DCH, kt0 + (cur ^ 1) * 16384, t);
      stage_tile512(qb + (size_t)n0 * DCH + (kidx + 1) * 64, DCH, qt0 + (cur ^ 1) * 16384, t);
      asm volatile("s_waitcnt vmcnt(8)" ::: "memory");
    } else {
      asm volatile("s_waitcnt vmcnt(0)" ::: "memory");
    }
    __builtin_amdgcn_s_barrier();
    asm volatile("" ::: "memory");
    for (int kk = 0; kk < 2; kk++) {
      bf16x8 af[8], bfr[4];
      int sw = ((kk * 4 + quad) ^ l7) * 8;
      for (int f = 0; f < 8; f++)
        af[f]  = *(const bf16x8*)&kt0[cur*16384 + (wm*128 + f*16 + l15)*64 + sw];
      for (int f = 0; f < 4; f++)
        bfr[f] = *(const bf16x8*)&qt0[cur*16384 + (wn*64 + f*16 + l15)*64 + sw];
      for (int fm = 0; fm < 8; fm++)
        for (int fn = 0; fn < 4; fn++)
          acc[fm][fn] = __builtin_amdgcn_mfma_f32_16x16x32_bf16(af[fm], bfr[fn], acc[fm][fn], 0, 0, 0);
    }
    asm volatile("" ::: "memory");
    __builtin_amdgcn_s_barrier();
  }

  // ---- epilogue: exp -> swizzled LDS tile ep[n][m] (256x256 bf16 = 128 KB) ----
  bf16* ep = smem;
  for (int fm = 0; fm < 8; fm++)
    for (int fn = 0; fn < 4; fn++) {
      int n_loc = wn*64 + fn*16 + l15;                 // C col = B(q) row = n
      int mby  = (wm*128 + fm*16 + quad*4) * 2;       // C row = A(k) row = m
      int addr = n_loc * 512 + mby;
      addr ^= (n_loc & 7) << 4;
      bf16x4 pk;
      for (int r = 0; r < 4; r++) pk[r] = (bf16)__expf(acc[fm][fn][r]);
      *(bf16x4*)((char*)ep + addr) = pk;
    }
  __syncthreads();
  // coalesced read-back: dense E store + rowsum via half-wave reduce
#pragma unroll
  for (int i = 0; i < 16; i++) {
    int slot = i * 512 + t;
    int nr = slot >> 5, c = slot & 31;
    int addr = nr * 512 + c * 16;
    addr ^= (nr & 7) << 4;
    bf16x8 v = *(const bf16x8*)((char*)ep + addr);
    *(bf16x8*)(E + (size_t)(n0 + nr) * NPIX + m0 + c * 8) = v;
    float s = 0.f;
    for (int j = 0; j < 8; j++) s += (float)v[j];
    s += __shfl_xor(s, 1); s += __shfl_xor(s, 2); s += __shfl_xor(s, 4);
    s += __shfl_xor(s, 8); s += __shfl_xor(s, 16);
    if ((t & 31) == 0) rp[n0 + nr] = s;
  }

  // ---- fused col_pass: last block of stripe (b,by) computes cpart[b][by][m] ----
  __threadfence();                                     // publish E stripe chunk + rp
  if (t == 0) lastflag = (atomicAdd(&ctrA[b * 16 + by], 1) == 15);
  __syncthreads();
  if (!lastflag) return;
  __threadfence();                                     // acquire siblings' E + rp
  float* eusf = (float*)smem;                          // reuse staging LDS (1 KB)
  if (t < 256) {
    float s = 0.f;
    const float* rpb = rowpartG + (size_t)b * 16 * NPIX + n0 + t;
    for (int mi = 0; mi < 16; mi++) s += rpb[(size_t)mi * NPIX];
    eusf[t] = __expf(logm - __logf(s));
  }
  __syncthreads();
  float a[8];
#pragma unroll
  for (int j = 0; j < 8; j++) a[j] = 0.f;
  const bf16* Erow = E + (size_t)n0 * NPIX + t * 8;    // stripe rows, full m width (4096)
  for (int r = 0; r < 256; r++) {
    float eu = eusf[r];
    bf16x8 ev = *(const bf16x8*)(Erow + (size_t)r * NPIX);
    for (int j = 0; j < 8; j++) a[j] += eu * (float)ev[j];
  }
  float* cpo = cpart + ((size_t)b * 16 + by) * NPIX + t * 8;
  float4 o0 = {a[0], a[1], a[2], a[3]};
  float4 o1 = {a[4], a[5], a[6], a[7]};
  *(float4*)(cpo) = o0;
  *(float4*)(cpo + 4) = o1;
}

// ============ K4: v''T[d][m] = exp(vpot[m]) * v[m][d] ============
__global__ __launch_bounds__(256) void vpp_kernel(
    const bf16* __restrict__ vb, const float* __restrict__ colpartG,
    bf16* __restrict__ vppT, float logm)
{
  __shared__ float ts[64][65];
  __shared__ float ef[64];
  const int b = blockIdx.z;
  vb += (size_t)b * NPIX * DCH;
  const float* cp = colpartG + (size_t)b * 16 * NPIX;
  vppT += (size_t)b * DCH * NPIX;
  const int t = threadIdx.x;
  const int m0 = blockIdx.x * 64, d0 = blockIdx.y * 64;
  if (t < 64) {
    float s = 0.f;
    for (int g = 0; g < 16; g++) s += cp[(size_t)g * NPIX + m0 + t];
    ef[t] = __expf(logm - __logf(s));
  }
  __syncthreads();
  for (int i = 0; i < 2; i++) {
    int slot = t + i * 256;
    int m = slot >> 3, dq = (slot & 7) * 8;
    bf16x8 v = *(const bf16x8*)(vb + (size_t)(m0 + m) * DCH + d0 + dq);
    float s = ef[m];
    for (int j = 0; j < 8; j++) ts[dq + j][m] = s * (float)v[j];
  }
  __syncthreads();
  for (int i = 0; i < 2; i++) {
    int slot = t + i * 256;
    int d = slot >> 3, mq = (slot & 7) * 8;
    bf16x8 pk;
    for (int j = 0; j < 8; j++) pk[j] = (bf16)ts[d][mq + j];
    *(bf16x8*)(vppT + (size_t)(d0 + d) * NPIX + m0 + mq) = pk;
  }
}

// ============ K5: pass C — 128n x 256d per block, 8 waves, dbuf. E read ONCE.
//   part[b][kc][d][n] = bf16( exp(u[n]) * (E_chunk @ v'')[n][d] ).
//   FUSED reduce: the 4th (last) block of each (b,nx) group sums the 4 partials -> f32 out. ============
__global__ __launch_bounds__(512, 2) void pass_c(
    const bf16* __restrict__ E, const bf16* __restrict__ vppT,
    const float* __restrict__ rowpartG, bf16* __restrict__ part,
    float* __restrict__ outp, int* __restrict__ ctrC, float logm)
{
  __shared__ bf16 smem[49152];   // 96 KB: [2] et 128x64 | [2] vt 256x64 ; epilogue: ept 256x128
  __shared__ float eus[128];
  __shared__ int lastflag;
  const int nx = (int)blockIdx.x >> 2, kc = (int)blockIdx.x & 3;  // kc fastest -> groups close staggered
  const int b = blockIdx.z;
  E += (size_t)b * NPIX * NPIX;
  vppT += (size_t)b * DCH * NPIX;
  const float* rpg = rowpartG + (size_t)b * 16 * NPIX;
  const bf16* partB = part + (size_t)b * 4 * DCH * NPIX;
  bf16* partBlk = part + (size_t)(b * 4 + kc) * DCH * NPIX;
  const int t  = threadIdx.x;
  const int n0 = nx * 128;
  const int mstart = kc * 1024;
  if (t < 128) {
    float s = 0.f;
    for (int mi = 0; mi < 16; mi++) s += rpg[(size_t)mi * NPIX + n0 + t];
    eus[t] = __expf(logm - __logf(s));
  }
  const int lane = t & 63, wave = t >> 6;
  const int wn = wave >> 2, wd = wave & 3;
  const int l15 = lane & 15, quad = lane >> 4;
  const int l7 = l15 & 7;
  bf16* et0 = smem;              // [2][8192]
  bf16* vt0 = smem + 16384;      // [2][16384]

  floatx4 acc[4][4];
  for (int i=0;i<4;i++) for (int j=0;j<4;j++) for (int r=0;r<4;r++) acc[i][j][r] = 0.f;
  __syncthreads();               // eus written before pipelined loop / epilogue smem reuse

  stage_tile128_512(E + (size_t)n0 * NPIX + mstart, NPIX, et0, t);
  stage_tile512(vppT + mstart, NPIX, vt0, t);

#pragma unroll 4
  for (int kidx = 0; kidx < 16; kidx++) {
    const int cur = kidx & 1;
    if (kidx < 15) {
      const int kn = mstart + (kidx + 1) * 64;
      stage_tile128_512(E + (size_t)n0 * NPIX + kn, NPIX, et0 + (cur ^ 1) * 8192, t);
      stage_tile512(vppT + kn, NPIX, vt0 + (cur ^ 1) * 16384, t);
      asm volatile("s_waitcnt vmcnt(6)" ::: "memory");
    } else {
      asm volatile("s_waitcnt vmcnt(0)" ::: "memory");
    }
    __builtin_amdgcn_s_barrier();
    asm volatile("" ::: "memory");
    for (int kk = 0; kk < 2; kk++) {
      bf16x8 af[4], bfr[4];
      int sw = ((kk * 4 + quad) ^ l7) * 8;
      for (int f = 0; f < 4; f++)
        af[f]  = *(const bf16x8*)&et0[cur*8192  + (wn*64 + f*16 + l15)*64 + sw];
      for (int f = 0; f < 4; f++)
        bfr[f] = *(const bf16x8*)&vt0[cur*16384 + (wd*64 + f*16 + l15)*64 + sw];
      for (int fn = 0; fn < 4; fn++)
        for (int fd = 0; fd < 4; fd++)
          acc[fn][fd] = __builtin_amdgcn_mfma_f32_16x16x32_bf16(af[fn], bfr[fd], acc[fn][fd], 0, 0, 0);
    }
    asm volatile("" ::: "memory");
    __builtin_amdgcn_s_barrier();
  }

  // ---- epilogue: scale by exp(u[n]) -> swizzled LDS tile ept[d][n] (256x128 bf16 = 64 KB) ----
  bf16* ept = smem;
  for (int fn = 0; fn < 4; fn++)
    for (int fd = 0; fd < 4; fd++) {
      int d_loc = wd*64 + fd*16 + l15;
      int n_l   = wn*64 + fn*16 + quad*4;
      int addr = d_loc * 256 + n_l * 2;
      addr ^= (d_loc & 7) << 4;
      bf16x4 o;
      for (int r = 0; r < 4; r++) o[r] = (bf16)(acc[fn][fd][r] * eus[n_l + r]);
      *(bf16x4*)((char*)ept + addr) = o;
    }
  __syncthreads();
#pragma unroll
  for (int i = 0; i < 8; i++) {
    int slot = i * 512 + t;
    int dr = slot >> 4, c = slot & 15;
    int addr = dr * 256 + c * 16;
    addr ^= (dr & 7) << 4;
    bf16x8 v = *(const bf16x8*)((char*)ept + addr);
    *(bf16x8*)(partBlk + (size_t)dr * NPIX + n0 + c * 8) = v;
  }

  // ---- fused reduce: last block of group (b,nx) sums 4 partials -> f32 out ----
  __threadfence();
  if (t == 0) lastflag = (atomicAdd(&ctrC[b * 32 + nx], 1) == 3);
  __syncthreads();
  if (!lastflag) return;
  __threadfence();
  float* outb = outp + (size_t)b * DCH * NPIX;
#pragma unroll
  for (int i = 0; i < 8; i++) {
    int slot = i * 512 + t;
    int dr = slot >> 4, c = slot & 15;
    size_t off = (size_t)dr * NPIX + n0 + c * 8;
    float s[8];
#pragma unroll
    for (int j = 0; j < 8; j++) s[j] = 0.f;
    for (int kq = 0; kq < 4; kq++) {
      bf16x8 v = *(const bf16x8*)(partB + (size_t)kq * DCH * NPIX + off);
#pragma unroll
      for (int j = 0; j < 8; j++) s[j] += (float)v[j];
    }
    float4 o0 = {s[0], s[1], s[2], s[3]};
    float4 o1 = {s[4], s[5], s[6], s[7]};
    *(float4*)(outb + off) = o0;
    *(float4*)(outb + off + 4) = o1;
  }
}

extern "C" void kernel_launch(void* const* d_in, const int* in_sizes, int n_in,
                              void* d_out, int out_size, void* d_ws, size_t ws_size,
                              hipStream_t stream) {
  (void)in_sizes; (void)n_in; (void)out_size; (void)ws_size;
  const float* x    = (const float*)d_in[0];
  const float* Wm   = (const float*)d_in[1];
  const float* bias = (const float*)d_in[2];
  float* outp = (float*)d_out;
  char* ws = (char*)d_ws;

  bf16*  xb   = (bf16*)(ws + OFF_XB);
  bf16*  wb   = (bf16*)(ws + OFF_WB);
  bf16*  qb   = (bf16*)(ws + OFF_Q);
  bf16*  kb   = (bf16*)(ws + OFF_K);
  bf16*  vb   = (bf16*)(ws + OFF_V);
  bf16*  E    = (bf16*)(ws + OFF_E);
  bf16*  vppT = (bf16*)(ws + OFF_VPP);
  float* rp   = (float*)(ws + OFF_RP);
  float* cp   = (float*)(ws + OFF_CP);
  int*   ctrs = (int*)(ws + OFF_CTR);
  bf16*  part = (bf16*)(ws + OFF_PART);
  int*   ctrA = ctrs;        // 32
  int*   ctrC = ctrs + 32;   // 64

  const float logm = logf(1.0f / 4096.0f + 1e-8f);

  prep<<<dim3(64, 5, 2), 256, 0, stream>>>(x, Wm, xb, wb, ctrs);
  conv_mfma<<<dim3(64, 6), 256, 0, stream>>>(xb, wb, bias, qb, kb, vb);

  pass_a<<<dim3(16, 16, 2), 512, 0, stream>>>(qb, kb, E, rp, cp, ctrA, logm);
  vpp_kernel<<<dim3(64, 4, 2), 256, 0, stream>>>(vb, cp, vppT, logm);
  pass_c<<<dim3(128, 1, 2), 512, 0, stream>>>(E, vppT, rp, part, outp, ctrC, logm);
}

// Round 8
// 149.424 us; speedup vs baseline: 2.5639x; 2.5639x over previous
//
#include <hip/hip_runtime.h>
#include <hip/hip_bf16.h>
#include <math.h>

typedef __bf16 bf16;
typedef __bf16 bf16x8 __attribute__((ext_vector_type(8)));
typedef __bf16 bf16x4 __attribute__((ext_vector_type(4)));
typedef float floatx4 __attribute__((ext_vector_type(4)));

typedef const __attribute__((address_space(1))) void* gas_t;
typedef __attribute__((address_space(3))) void* las_t;

#define NPIX 4096
#define DCH 256

// ---------------- workspace layout (bytes) ----------------
#define OFF_XB   ((size_t)0)            // bf16 [8192][256]      4 MB
#define OFF_WB   ((size_t)4194304)      // bf16 [768][256]       384 KB
#define OFF_Q    ((size_t)4587520)      // bf16 [8192][256]      4 MB
#define OFF_K    ((size_t)8781824)      // bf16 [8192][256]      4 MB
#define OFF_V    ((size_t)12976128)     // bf16 [8192][256]      4 MB
#define OFF_E    ((size_t)17170432)     // bf16 [2][4096][4096]  64 MB
#define OFF_VPP  ((size_t)84279296)     // bf16 [2][256][4096]   4 MB
#define OFF_RP   ((size_t)88473600)     // f32  [2][16][4096]    512 KB (rowsum partials per 256-m-tile)
#define OFF_CP   ((size_t)89522176)     // f32  [2][64][4096]    2 MB  (colsum partials per 64-row n-group)
#define OFF_PART ((size_t)91619328)     // bf16 [2][4][256][4096] 16 MB (split-K partials)

// global->LDS DMA staging, 16B/lane, XOR swizzle applied on the GLOBAL side
// (LDS dest must stay wave-uniform-base + lane*16). LDS[row][seg] = global[row][seg^(row&7)].
// 256-thread variant: 128 rows x 64 cols per call (4 loads/thread).
__device__ __forceinline__ void stage_tile(const bf16* __restrict__ g0, size_t rstride,
                                           bf16* lds, int t) {
  const int wbase = (t >> 6) << 6;
#pragma unroll
  for (int i = 0; i < 4; i++) {
    int slot = i * 256 + t;
    int row = slot >> 3, seg = slot & 7;
    const bf16* g = g0 + (size_t)row * rstride + ((seg ^ (row & 7)) << 3);
    bf16* l = lds + (size_t)(i * 256 + wbase) * 8;
    __builtin_amdgcn_global_load_lds((gas_t)g, (las_t)l, 16, 0, 0);
  }
}

// 512-thread variant: 256 rows x 64 cols per call (4 loads/thread).
__device__ __forceinline__ void stage_tile512(const bf16* __restrict__ g0, size_t rstride,
                                              bf16* lds, int t) {
  const int wbase = (t >> 6) << 6;
#pragma unroll
  for (int i = 0; i < 4; i++) {
    int slot = i * 512 + t;
    int row = slot >> 3, seg = slot & 7;
    const bf16* g = g0 + (size_t)row * rstride + ((seg ^ (row & 7)) << 3);
    bf16* l = lds + (size_t)(i * 512 + wbase) * 8;
    __builtin_amdgcn_global_load_lds((gas_t)g, (las_t)l, 16, 0, 0);
  }
}

// 512-thread variant: 128 rows x 64 cols per call (2 loads/thread).
__device__ __forceinline__ void stage_tile128_512(const bf16* __restrict__ g0, size_t rstride,
                                                  bf16* lds, int t) {
  const int wbase = (t >> 6) << 6;
#pragma unroll
  for (int i = 0; i < 2; i++) {
    int slot = i * 512 + t;
    int row = slot >> 3, seg = slot & 7;
    const bf16* g = g0 + (size_t)row * rstride + ((seg ^ (row & 7)) << 3);
    bf16* l = lds + (size_t)(i * 512 + wbase) * 8;
    __builtin_amdgcn_global_load_lds((gas_t)g, (las_t)l, 16, 0, 0);
  }
}

// ============ K0: prep = transpose x to [n][c] bf16 (y<4) + convert W to bf16 (y==4) ============
__global__ __launch_bounds__(256) void prep(
    const float* __restrict__ x, const float* __restrict__ W,
    bf16* __restrict__ xb, bf16* __restrict__ wb)
{
  const int t = threadIdx.x;
  if (blockIdx.y == 4) {
    int gid = (blockIdx.z * 64 + blockIdx.x) * 256 + t;
    for (int i = gid; i < 49152; i += 32768) {
      float4 v = *(const float4*)(W + (size_t)i * 4);
      bf16x4 pk = { (bf16)v.x, (bf16)v.y, (bf16)v.z, (bf16)v.w };
      *(bf16x4*)(wb + (size_t)i * 4) = pk;
    }
    return;
  }
  __shared__ float ts[64][65];
  const int b = blockIdx.z, n0 = blockIdx.x * 64, c0 = blockIdx.y * 64;
  const float* xp = x + ((size_t)b * DCH + c0) * NPIX + n0;
  for (int i = 0; i < 4; i++) {
    int slot = t + i * 256;
    int c = slot >> 4, nq = (slot & 15) * 4;
    float4 v = *(const float4*)(xp + (size_t)c * NPIX + nq);
    ts[c][nq + 0] = v.x; ts[c][nq + 1] = v.y; ts[c][nq + 2] = v.z; ts[c][nq + 3] = v.w;
  }
  __syncthreads();
  for (int i = 0; i < 2; i++) {
    int slot = t + i * 256;
    int n = slot >> 3, cq = (slot & 7) * 8;
    bf16x8 pk;
    for (int j = 0; j < 8; j++) pk[j] = (bf16)ts[cq + j][n];
    *(bf16x8*)(xb + ((size_t)b * NPIX + n0 + n) * DCH + c0 + cq) = pk;
  }
}

// ============ K1: 1x1 conv as bf16 MFMA GEMM (pipelined dbuf) ============
__global__ __launch_bounds__(256) void conv_mfma(
    const bf16* __restrict__ xb, const bf16* __restrict__ wb,
    const float* __restrict__ bias,
    bf16* __restrict__ qb, bf16* __restrict__ kb, bf16* __restrict__ vb)
{
  __shared__ bf16 at[2][128 * 64];
  __shared__ bf16 bt[2][128 * 64];
  __shared__ float bs[128];
  const int t  = threadIdx.x;
  const int n0 = blockIdx.x * 128;
  const int o0 = blockIdx.y * 128;
  if (t < 128) bs[t] = bias[o0 + t];
  const int lane = t & 63, wave = t >> 6;
  const int wm = wave >> 1, wn = wave & 1;
  const int l15 = lane & 15, quad = lane >> 4;
  const int l7 = l15 & 7;

  stage_tile(wb + (size_t)o0 * DCH, DCH, at[0], t);
  stage_tile(xb + (size_t)n0 * DCH, DCH, bt[0], t);

  floatx4 acc[4][4];
  for (int i=0;i<4;i++) for (int j=0;j<4;j++) for (int r=0;r<4;r++) acc[i][j][r] = 0.f;

#pragma unroll
  for (int kidx = 0; kidx < 4; kidx++) {
    const int cur = kidx & 1;
    if (kidx < 3) {
      stage_tile(wb + (size_t)o0 * DCH + (kidx + 1) * 64, DCH, at[cur ^ 1], t);
      stage_tile(xb + (size_t)n0 * DCH + (kidx + 1) * 64, DCH, bt[cur ^ 1], t);
      asm volatile("s_waitcnt vmcnt(8)" ::: "memory");
    } else {
      asm volatile("s_waitcnt vmcnt(0)" ::: "memory");
    }
    __builtin_amdgcn_s_barrier();
    asm volatile("" ::: "memory");
    for (int kk = 0; kk < 2; kk++) {
      bf16x8 af[4], bfr[4];
      int sw = ((kk * 4 + quad) ^ l7) * 8;
      for (int f = 0; f < 4; f++)
        af[f]  = *(const bf16x8*)&at[cur][(wm*64 + f*16 + l15)*64 + sw];
      for (int f = 0; f < 4; f++)
        bfr[f] = *(const bf16x8*)&bt[cur][(wn*64 + f*16 + l15)*64 + sw];
      for (int fm = 0; fm < 4; fm++)
        for (int fn = 0; fn < 4; fn++)
          acc[fm][fn] = __builtin_amdgcn_mfma_f32_16x16x32_bf16(af[fm], bfr[fn], acc[fm][fn], 0, 0, 0);
    }
    asm volatile("" ::: "memory");
    __builtin_amdgcn_s_barrier();
  }

  const float scale = (o0 < 512) ? 0.25f : 1.0f;
  bf16* dst; int od;
  if (o0 < 256)      { dst = qb; od = o0; }
  else if (o0 < 512) { dst = kb; od = o0 - 256; }
  else               { dst = vb; od = o0 - 512; }

  for (int fm = 0; fm < 4; fm++)
    for (int fn = 0; fn < 4; fn++) {
      int o_l = wm*64 + fm*16 + quad*4;
      int n_g = n0 + wn*64 + fn*16 + l15;
      bf16x4 pk;
      for (int r = 0; r < 4; r++)
        pk[r] = (bf16)((acc[fm][fn][r] + bs[o_l + r]) * scale);
      *(bf16x4*)(dst + (size_t)n_g * DCH + od + o_l) = pk;
    }
}

// ============ K2: pass A — 256x256 tile, 8 waves. E = exp(q k^T) via LDS-transpose epilogue;
//               rowpart[b][m_tile][n] from the coalesced read-back. ============
__global__ __launch_bounds__(512, 2) void pass_a(
    const bf16* __restrict__ qb, const bf16* __restrict__ kb,
    bf16* __restrict__ E, float* __restrict__ rowpartG)
{
  __shared__ bf16 smem[65536];   // 128 KB: [2] kt 256x64 | [2] qt 256x64 ; epilogue: ep 256x256
  // XCD-bijective swizzle (512 % 8 == 0): XCD x gets contiguous flat range -> kb strip stays L2-hot
  int flat = (int)blockIdx.x + ((int)blockIdx.y << 4) + ((int)blockIdx.z << 8);
  flat = (flat & 7) * 64 + (flat >> 3);
  const int bx = flat & 15, by = (flat >> 4) & 15, b = flat >> 8;
  qb += (size_t)b * NPIX * DCH;
  kb += (size_t)b * NPIX * DCH;
  E  += (size_t)b * NPIX * NPIX;
  float* rp = rowpartG + ((size_t)b * 16 + bx) * NPIX;
  const int t  = threadIdx.x;
  const int m0 = bx * 256;
  const int n0 = by * 256;
  const int lane = t & 63, wave = t >> 6;
  const int wm = wave >> 2, wn = wave & 3;       // 2 m-halves x 4 n-quarters
  const int l15 = lane & 15, quad = lane >> 4;
  const int l7 = l15 & 7;
  bf16* kt0 = smem;              // [2][16384]
  bf16* qt0 = smem + 32768;      // [2][16384]

  stage_tile512(kb + (size_t)m0 * DCH, DCH, kt0, t);
  stage_tile512(qb + (size_t)n0 * DCH, DCH, qt0, t);

  floatx4 acc[8][4];
  for (int i=0;i<8;i++) for (int j=0;j<4;j++) for (int r=0;r<4;r++) acc[i][j][r] = 0.f;

#pragma unroll
  for (int kidx = 0; kidx < 4; kidx++) {
    const int cur = kidx & 1;
    if (kidx < 3) {
      stage_tile512(kb + (size_t)m0 * DCH + (kidx + 1) * 64, DCH, kt0 + (cur ^ 1) * 16384, t);
      stage_tile512(qb + (size_t)n0 * DCH + (kidx + 1) * 64, DCH, qt0 + (cur ^ 1) * 16384, t);
      asm volatile("s_waitcnt vmcnt(8)" ::: "memory");
    } else {
      asm volatile("s_waitcnt vmcnt(0)" ::: "memory");
    }
    __builtin_amdgcn_s_barrier();
    asm volatile("" ::: "memory");
    for (int kk = 0; kk < 2; kk++) {
      bf16x8 af[8], bfr[4];
      int sw = ((kk * 4 + quad) ^ l7) * 8;
      for (int f = 0; f < 8; f++)
        af[f]  = *(const bf16x8*)&kt0[cur*16384 + (wm*128 + f*16 + l15)*64 + sw];
      for (int f = 0; f < 4; f++)
        bfr[f] = *(const bf16x8*)&qt0[cur*16384 + (wn*64 + f*16 + l15)*64 + sw];
      for (int fm = 0; fm < 8; fm++)
        for (int fn = 0; fn < 4; fn++)
          acc[fm][fn] = __builtin_amdgcn_mfma_f32_16x16x32_bf16(af[fm], bfr[fn], acc[fm][fn], 0, 0, 0);
    }
    asm volatile("" ::: "memory");
    __builtin_amdgcn_s_barrier();
  }

  // ---- epilogue: exp -> swizzled LDS tile ep[n][m] (256x256 bf16 = 128 KB, reuses staging LDS) ----
  bf16* ep = smem;
  for (int fm = 0; fm < 8; fm++)
    for (int fn = 0; fn < 4; fn++) {
      int n_loc = wn*64 + fn*16 + l15;                 // C col = B(q) row = n
      int mby  = (wm*128 + fm*16 + quad*4) * 2;       // C row = A(k) row = m; byte offset in row
      int addr = n_loc * 512 + mby;
      addr ^= (n_loc & 7) << 4;                       // 16B-granule XOR swizzle
      bf16x4 pk;
      for (int r = 0; r < 4; r++) pk[r] = (bf16)__expf(acc[fm][fn][r]);
      *(bf16x4*)((char*)ep + addr) = pk;
    }
  __syncthreads();
  // coalesced read-back: store E dense (1 KB/wave-instr) + rowsum via half-wave reduce
#pragma unroll
  for (int i = 0; i < 16; i++) {
    int slot = i * 512 + t;
    int nr = slot >> 5, c = slot & 31;                // 32 x 16B chunks per 512B row
    int addr = nr * 512 + c * 16;
    addr ^= (nr & 7) << 4;
    bf16x8 v = *(const bf16x8*)((char*)ep + addr);
    *(bf16x8*)(E + (size_t)(n0 + nr) * NPIX + m0 + c * 8) = v;
    float s = 0.f;
    for (int j = 0; j < 8; j++) s += (float)v[j];
    s += __shfl_xor(s, 1); s += __shfl_xor(s, 2); s += __shfl_xor(s, 4);
    s += __shfl_xor(s, 8); s += __shfl_xor(s, 16);
    if ((t & 31) == 0) rp[n0 + nr] = s;               // one half-wave per row, deterministic
  }
}

// ============ K3: colpart[b][ng][m] = sum over 64-row group of exp(u_n)*E[n][m], 16B loads ============
__global__ __launch_bounds__(256) void col_pass(
    const bf16* __restrict__ E, const float* __restrict__ rowpartG,
    float* __restrict__ colpartG, float logm)
{
  __shared__ float eus[64];
  const int b = blockIdx.z;
  E += (size_t)b * NPIX * NPIX;
  const float* rp = rowpartG + (size_t)b * 16 * NPIX;
  float* cp = colpartG + ((size_t)b * 64 + blockIdx.y) * NPIX;
  const int t = threadIdx.x;
  const int col = blockIdx.x * 2048 + t * 8;
  const int nbase = blockIdx.y * 64;
  if (t < 64) {
    float s = 0.f;
    for (int mi = 0; mi < 16; mi++) s += rp[(size_t)mi * NPIX + nbase + t];
    eus[t] = __expf(logm - __logf(s));
  }
  __syncthreads();
  float a[8] = {0.f,0.f,0.f,0.f,0.f,0.f,0.f,0.f};
#pragma unroll 4
  for (int r = 0; r < 64; r++) {
    float eu = eus[r];
    bf16x8 ev = *(const bf16x8*)(E + (size_t)(nbase + r) * NPIX + col);
    for (int j = 0; j < 8; j++) a[j] += eu * (float)ev[j];
  }
  float4 o0 = {a[0], a[1], a[2], a[3]};
  float4 o1 = {a[4], a[5], a[6], a[7]};
  *(float4*)(cp + col) = o0;
  *(float4*)(cp + col + 4) = o1;
}

// ============ K4: v''T[d][m] = exp(vpot[m]) * v[m][d] ============
__global__ __launch_bounds__(256) void vpp_kernel(
    const bf16* __restrict__ vb, const float* __restrict__ colpartG,
    bf16* __restrict__ vppT, float logm)
{
  __shared__ float ts[64][65];
  __shared__ float ef[64];
  const int b = blockIdx.z;
  vb += (size_t)b * NPIX * DCH;
  const float* cp = colpartG + (size_t)b * 64 * NPIX;
  vppT += (size_t)b * DCH * NPIX;
  const int t = threadIdx.x;
  const int m0 = blockIdx.x * 64, d0 = blockIdx.y * 64;
  if (t < 64) {
    float s = 0.f;
    for (int g = 0; g < 64; g++) s += cp[(size_t)g * NPIX + m0 + t];
    ef[t] = __expf(logm - __logf(s));
  }
  __syncthreads();
  for (int i = 0; i < 2; i++) {
    int slot = t + i * 256;
    int m = slot >> 3, dq = (slot & 7) * 8;
    bf16x8 v = *(const bf16x8*)(vb + (size_t)(m0 + m) * DCH + d0 + dq);
    float s = ef[m];
    for (int j = 0; j < 8; j++) ts[dq + j][m] = s * (float)v[j];
  }
  __syncthreads();
  for (int i = 0; i < 2; i++) {
    int slot = t + i * 256;
    int d = slot >> 3, mq = (slot & 7) * 8;
    bf16x8 pk;
    for (int j = 0; j < 8; j++) pk[j] = (bf16)ts[d][mq + j];
    *(bf16x8*)(vppT + (size_t)(d0 + d) * NPIX + m0 + mq) = pk;
  }
}

// ============ K5: pass C — 128n x 256d (full d) per block, 8 waves. E read ONCE.
//               part[b][kc][d][n] = bf16( exp(u[n]) * (E_chunk @ v'')[n][d] ) ============
__global__ __launch_bounds__(512, 2) void pass_c(
    const bf16* __restrict__ E, const bf16* __restrict__ vppT,
    const float* __restrict__ rowpartG, bf16* __restrict__ part, float logm)
{
  __shared__ bf16 smem[49152];   // 96 KB: [2] et 128x64 | [2] vt 256x64 ; epilogue: ept 256x128
  __shared__ float eus[128];
  const int z = blockIdx.z;
  const int b = z >> 2, kc = z & 3;
  E += (size_t)b * NPIX * NPIX;
  vppT += (size_t)b * DCH * NPIX;
  const float* rpg = rowpartG + (size_t)b * 16 * NPIX;
  part += (size_t)(b * 4 + kc) * DCH * NPIX;
  const int t  = threadIdx.x;
  const int n0 = blockIdx.x * 128;
  const int mstart = kc * 1024;
  if (t < 128) {
    float s = 0.f;
    for (int mi = 0; mi < 16; mi++) s += rpg[(size_t)mi * NPIX + n0 + t];
    eus[t] = __expf(logm - __logf(s));
  }
  const int lane = t & 63, wave = t >> 6;
  const int wn = wave >> 2, wd = wave & 3;        // 2 n-halves x 4 d-quarters
  const int l15 = lane & 15, quad = lane >> 4;
  const int l7 = l15 & 7;
  bf16* et0 = smem;              // [2][8192]
  bf16* vt0 = smem + 16384;      // [2][16384]

  floatx4 acc[4][4];
  for (int i=0;i<4;i++) for (int j=0;j<4;j++) for (int r=0;r<4;r++) acc[i][j][r] = 0.f;
  __syncthreads();               // eus written before pipelined loop / epilogue smem reuse

  stage_tile128_512(E + (size_t)n0 * NPIX + mstart, NPIX, et0, t);
  stage_tile512(vppT + mstart, NPIX, vt0, t);

#pragma unroll 4
  for (int kidx = 0; kidx < 16; kidx++) {
    const int cur = kidx & 1;
    if (kidx < 15) {
      const int kn = mstart + (kidx + 1) * 64;
      stage_tile128_512(E + (size_t)n0 * NPIX + kn, NPIX, et0 + (cur ^ 1) * 8192, t);
      stage_tile512(vppT + kn, NPIX, vt0 + (cur ^ 1) * 16384, t);
      asm volatile("s_waitcnt vmcnt(6)" ::: "memory");
    } else {
      asm volatile("s_waitcnt vmcnt(0)" ::: "memory");
    }
    __builtin_amdgcn_s_barrier();
    asm volatile("" ::: "memory");
    for (int kk = 0; kk < 2; kk++) {
      bf16x8 af[4], bfr[4];
      int sw = ((kk * 4 + quad) ^ l7) * 8;
      for (int f = 0; f < 4; f++)
        af[f]  = *(const bf16x8*)&et0[cur*8192  + (wn*64 + f*16 + l15)*64 + sw];
      for (int f = 0; f < 4; f++)
        bfr[f] = *(const bf16x8*)&vt0[cur*16384 + (wd*64 + f*16 + l15)*64 + sw];
      for (int fn = 0; fn < 4; fn++)
        for (int fd = 0; fd < 4; fd++)
          acc[fn][fd] = __builtin_amdgcn_mfma_f32_16x16x32_bf16(af[fn], bfr[fd], acc[fn][fd], 0, 0, 0);
    }
    asm volatile("" ::: "memory");
    __builtin_amdgcn_s_barrier();
  }

  // ---- epilogue: scale by exp(u[n]) -> swizzled LDS tile ept[d][n] (256x128 bf16 = 64 KB) ----
  bf16* ept = smem;
  for (int fn = 0; fn < 4; fn++)
    for (int fd = 0; fd < 4; fd++) {
      int d_loc = wd*64 + fd*16 + l15;               // C col = B(vpp) row = d
      int n_l   = wn*64 + fn*16 + quad*4;            // C row = A(E) row = n
      int addr = d_loc * 256 + n_l * 2;
      addr ^= (d_loc & 7) << 4;
      bf16x4 o;
      for (int r = 0; r < 4; r++) o[r] = (bf16)(acc[fn][fd][r] * eus[n_l + r]);
      *(bf16x4*)((char*)ept + addr) = o;
    }
  __syncthreads();
#pragma unroll
  for (int i = 0; i < 8; i++) {
    int slot = i * 512 + t;
    int dr = slot >> 4, c = slot & 15;               // 16 x 16B chunks per 256B row
    int addr = dr * 256 + c * 16;
    addr ^= (dr & 7) << 4;
    bf16x8 v = *(const bf16x8*)((char*)ept + addr);
    *(bf16x8*)(part + (size_t)dr * NPIX + n0 + c * 8) = v;
  }
}

// ============ K6: reduce split-K partials (both batches), bf16 -> f32 ============
__global__ __launch_bounds__(256) void reduce_k(
    const bf16* __restrict__ part, float* __restrict__ outp)
{
  size_t i4 = ((size_t)blockIdx.x * 256 + threadIdx.x) * 4;
  size_t b = i4 >> 20;
  size_t off = i4 & (size_t)1048575;
  const bf16* p = part + b * 4 * (size_t)1048576 + off;
  bf16x4 a = *(const bf16x4*)(p);
  bf16x4 bq = *(const bf16x4*)(p + (size_t)1048576);
  bf16x4 c = *(const bf16x4*)(p + (size_t)2097152);
  bf16x4 d = *(const bf16x4*)(p + (size_t)3145728);
  float4 s = { (float)a[0]+(float)bq[0]+(float)c[0]+(float)d[0],
               (float)a[1]+(float)bq[1]+(float)c[1]+(float)d[1],
               (float)a[2]+(float)bq[2]+(float)c[2]+(float)d[2],
               (float)a[3]+(float)bq[3]+(float)c[3]+(float)d[3] };
  *(float4*)(outp + i4) = s;
}

extern "C" void kernel_launch(void* const* d_in, const int* in_sizes, int n_in,
                              void* d_out, int out_size, void* d_ws, size_t ws_size,
                              hipStream_t stream) {
  (void)in_sizes; (void)n_in; (void)out_size; (void)ws_size;
  const float* x    = (const float*)d_in[0];
  const float* Wm   = (const float*)d_in[1];
  const float* bias = (const float*)d_in[2];
  float* outp = (float*)d_out;
  char* ws = (char*)d_ws;

  bf16*  xb   = (bf16*)(ws + OFF_XB);
  bf16*  wb   = (bf16*)(ws + OFF_WB);
  bf16*  qb   = (bf16*)(ws + OFF_Q);
  bf16*  kb   = (bf16*)(ws + OFF_K);
  bf16*  vb   = (bf16*)(ws + OFF_V);
  bf16*  E    = (bf16*)(ws + OFF_E);
  bf16*  vppT = (bf16*)(ws + OFF_VPP);
  float* rp   = (float*)(ws + OFF_RP);
  float* cp   = (float*)(ws + OFF_CP);
  bf16*  part = (bf16*)(ws + OFF_PART);

  const float logm = logf(1.0f / 4096.0f + 1e-8f);

  prep<<<dim3(64, 5, 2), 256, 0, stream>>>(x, Wm, xb, wb);
  conv_mfma<<<dim3(64, 6), 256, 0, stream>>>(xb, wb, bias, qb, kb, vb);

  pass_a<<<dim3(16, 16, 2), 512, 0, stream>>>(qb, kb, E, rp);
  col_pass<<<dim3(2, 64, 2), 256, 0, stream>>>(E, rp, cp, logm);
  vpp_kernel<<<dim3(64, 4, 2), 256, 0, stream>>>(vb, cp, vppT, logm);
  pass_c<<<dim3(32, 1, 8), 512, 0, stream>>>(E, vppT, rp, part, logm);
  reduce_k<<<2048, 256, 0, stream>>>(part, outp);
}